// Round 9
// baseline (290.741 us; speedup 1.0000x reference)
//
#include <hip/hip_runtime.h>
#include <hip/hip_bf16.h>
#include <math.h>

#define BB 8
#define NN 4096
#define FF 100
#define DD 64
#define BK 64
#define RT 128    // rows per block tile

typedef __bf16 bf16x8 __attribute__((ext_vector_type(8)));
typedef float f32x4 __attribute__((ext_vector_type(4)));

// ---------------------------------------------------------------------------
// Kernel A: hT[b][d][m] = bf16( x[b,m,:] @ Wg[:,d] + bg[d] )  (transposed)
// Also zeroes pooled[] (blocks 0-1). (unchanged — verified)
// ---------------------------------------------------------------------------
__global__ __launch_bounds__(256) void kernA(
    const float* __restrict__ x, const float* __restrict__ Wg,
    const float* __restrict__ bg, __bf16* __restrict__ hT,
    float* __restrict__ pooled)
{
    __shared__ float lds[64][65];
    int tid = threadIdx.x;
    int g = blockIdx.x * 256 + tid;
    if (g < BB * DD) pooled[g] = 0.0f;

    int b  = blockIdx.x >> 6;
    int m0 = (blockIdx.x & 63) * 64;
    int d  = tid & 63;
    int mg = tid >> 6;

    float acc[16];
    float bias = bg[d];
    #pragma unroll
    for (int j = 0; j < 16; ++j) acc[j] = bias;

    const float* xbase = x + ((size_t)b * NN + m0 + mg * 16) * FF;
    for (int f4 = 0; f4 < FF / 4; ++f4) {
        float wg0 = Wg[(f4 * 4 + 0) * DD + d];
        float wg1 = Wg[(f4 * 4 + 1) * DD + d];
        float wg2 = Wg[(f4 * 4 + 2) * DD + d];
        float wg3 = Wg[(f4 * 4 + 3) * DD + d];
        #pragma unroll
        for (int j = 0; j < 16; ++j) {
            float4 xv = *reinterpret_cast<const float4*>(xbase + j * FF + f4 * 4);
            acc[j] += xv.x * wg0 + xv.y * wg1 + xv.z * wg2 + xv.w * wg3;
        }
    }
    #pragma unroll
    for (int j = 0; j < 16; ++j) lds[mg * 16 + j][d] = acc[j];
    __syncthreads();

    int lane = tid & 63;
    int dg   = tid >> 6;
    size_t obase = ((size_t)b * DD + dg * 16) * NN + m0 + lane;
    #pragma unroll
    for (int j = 0; j < 16; ++j)
        hT[obase + (size_t)j * NN] = (__bf16)lds[lane][dg * 16 + j];
}

// ---------------------------------------------------------------------------
// Kernel B v9 = R8 geometry, but REG-STAGED (T14): global_load_dwordx4 ->
// VGPR -> ds_write_b128, replacing global_load_lds whose measured per-instr
// cost was a constant ~60 ns across R4/R6/R8 (suspected LDS-DMA throughput
// cap ~16-20 GB/s/CU). Contiguous wave addresses (no TA scatter). Raw
// lgkmcnt(0)-only barrier — next tile's global loads stay in flight across
// it; compiler emits counted vmcnt before the ds_writes.
// 512 thr (8 waves), tile 128 rows x 64 d, BK=64, 2 LDS buffers (80 KB).
// Grid 256, XCD-bijective swizzle (bb = l&7).
// ---------------------------------------------------------------------------
__global__ __launch_bounds__(512) void kernB(
    const float* __restrict__ adj, const __bf16* __restrict__ hT,
    const float* __restrict__ mask, float* __restrict__ pooled)
{
    __shared__ float  aL[2][RT * BK];   // 2 x 32 KB
    __shared__ __bf16 hL[2][DD * BK];   // 2 x 8 KB

    int l   = blockIdx.x;               // 0..255
    int bb  = l & 7;                    // batch == XCD (l % 8 round-robin)
    int n0  = (l >> 3) * RT;            // rowgroup base
    int tid = threadIdx.x;
    int w    = tid >> 6;                // 0..7
    int lane = tid & 63;
    int l15  = lane & 15;
    int kg   = lane >> 4;
    int rowL = w * 16 + l15;            // 0..127
    int rsw  = rowL & 15;               // adj swizzle key
    int dsw  = l15 & 7;                 // hT swizzle key

    f32x4 acc[4];
    #pragma unroll
    for (int c = 0; c < 4; ++c) acc[c] = (f32x4){0.f, 0.f, 0.f, 0.f};

    const float*  adjB = adj + ((size_t)bb * NN + n0) * NN;
    const __bf16* hTB  = hT + (size_t)bb * DD * NN;

    // per-thread staging source pointers (advance by BK each step)
    const float* srcA[4];
    #pragma unroll
    for (int i = 0; i < 4; ++i) {
        int p    = i * 512 + tid;               // granule 0..2047
        int row  = p >> 4;
        int slot = p & 15;
        int ss   = slot ^ (row & 15);           // involution swizzle
        srcA[i]  = adjB + (size_t)row * NN + ss * 4;
    }
    const __bf16* srcH;
    {
        int p    = tid;                         // granule 0..511
        int d    = p >> 3;
        int slot = p & 7;
        int ss   = slot ^ (d & 7);
        srcH     = hTB + (size_t)d * NN + ss * 8;
    }

    float4 rg[5];
    auto load_tile = [&](int k0) {
        #pragma unroll
        for (int i = 0; i < 4; ++i)
            rg[i] = *reinterpret_cast<const float4*>(srcA[i] + k0);
        rg[4] = *reinterpret_cast<const float4*>(srcH + k0);
    };
    auto write_tile = [&](int buf) {
        #pragma unroll
        for (int i = 0; i < 4; ++i) {
            int p = i * 512 + tid;
            *reinterpret_cast<float4*>((char*)(&aL[buf][0]) + (size_t)p * 16) = rg[i];
        }
        *reinterpret_cast<float4*>((char*)(&hL[buf][0]) + (size_t)tid * 16) = rg[4];
    };

    const int NSTEP = NN / BK;          // 64
    load_tile(0);
    write_tile(0);
    load_tile(BK);
    __syncthreads();                    // prologue: buf0 ready (full drain ok)

    for (int step = 0; step < NSTEP; ++step) {
        int cur = step & 1;

        // ---- compute tile `step` from buf[cur] ----
        const float*  aB = &aL[cur][rowL * BK];
        const __bf16* hB = &hL[cur][0];
        #pragma unroll
        for (int kk = 0; kk < 2; ++kk) {
            int s0 = kk * 8 + kg * 2;
            f32x4 alo = *(const f32x4*)(aB + ((s0    ) ^ rsw) * 4);
            f32x4 ahi = *(const f32x4*)(aB + ((s0 + 1) ^ rsw) * 4);
            bf16x8 af;
            af[0] = (__bf16)alo[0]; af[1] = (__bf16)alo[1];
            af[2] = (__bf16)alo[2]; af[3] = (__bf16)alo[3];
            af[4] = (__bf16)ahi[0]; af[5] = (__bf16)ahi[1];
            af[6] = (__bf16)ahi[2]; af[7] = (__bf16)ahi[3];
            int slB = (kk * 4 + kg) ^ dsw;
            #pragma unroll
            for (int c = 0; c < 4; ++c) {
                const __bf16* bp = hB + (c * 16 + l15) * BK + slB * 8;
                acc[c] = __builtin_amdgcn_mfma_f32_16x16x32_bf16(
                    af, *(const bf16x8*)bp, acc[c], 0, 0, 0);
            }
        }

        // ---- stage tile step+1 into buf[cur^1]; issue loads for step+2 ----
        if (step + 1 < NSTEP) {
            write_tile(cur ^ 1);        // compiler inserts counted vmcnt
            if (step + 2 < NSTEP) load_tile((step + 2) * BK);
        }
        // barrier WITHOUT vmcnt drain: in-flight loads target registers only
        asm volatile("s_waitcnt lgkmcnt(0)" ::: "memory");
        __builtin_amdgcn_s_barrier();
    }

    // Epilogue: D layout col = lane&15, row = (lane>>4)*4 + j  [m89 verified]
    float mk[4];
    int growbase = n0 + w * 16 + kg * 4;
    #pragma unroll
    for (int j = 0; j < 4; ++j) mk[j] = mask[bb * NN + growbase + j];
    #pragma unroll
    for (int c = 0; c < 4; ++c) {
        float s = 0.f;
        #pragma unroll
        for (int j = 0; j < 4; ++j) s += fmaxf(acc[c][j], 0.f) * mk[j];
        s += __shfl_xor(s, 16);
        s += __shfl_xor(s, 32);
        if (lane < 16)
            atomicAdd(&pooled[bb * DD + c * 16 + lane], s);
    }
}

// ---------------------------------------------------------------------------
// Kernel C: pooled normalize + time MLP + classifier + sigmoid. 1 block.
// ---------------------------------------------------------------------------
__global__ __launch_bounds__(512) void kernC(
    const float* __restrict__ mask, const float* __restrict__ t_in,
    const float* __restrict__ Wt, const float* __restrict__ bt,
    const float* __restrict__ W0, const float* __restrict__ b0,
    const float* __restrict__ W1, const float* __restrict__ b1,
    const float* __restrict__ W2, const float* __restrict__ b2,
    const float* __restrict__ pooled, float* __restrict__ out)
{
    __shared__ float msum[BB];
    __shared__ float zs[BB][2 * DD];
    __shared__ float z1s[BB][DD];
    __shared__ float z2s[BB][DD];

    int tid  = threadIdx.x;
    int b    = tid >> 6;
    int lane = tid & 63;

    float s = 0.f;
    for (int i = lane; i < NN; i += 64) s += mask[b * NN + i];
    s += __shfl_xor(s, 32); s += __shfl_xor(s, 16);
    s += __shfl_xor(s, 8);  s += __shfl_xor(s, 4);
    s += __shfl_xor(s, 2);  s += __shfl_xor(s, 1);
    if (lane == 0) msum[b] = s;
    __syncthreads();

    float ms  = fmaxf(msum[b], 1.0f);
    float pv  = pooled[b * DD + lane] / ms;
    float tev = t_in[b] * Wt[lane] + bt[lane];
    zs[b][lane]      = pv;
    zs[b][DD + lane] = tev;
    __syncthreads();

    float a = b0[lane];
    for (int f = 0; f < 2 * DD; ++f) a += zs[b][f] * W0[f * DD + lane];
    z1s[b][lane] = fmaxf(a, 0.f);
    __syncthreads();

    a = b1[lane];
    for (int f = 0; f < DD; ++f) a += z1s[b][f] * W1[f * DD + lane];
    z2s[b][lane] = fmaxf(a, 0.f);
    __syncthreads();

    if (lane == 0) {
        float o = b2[0];
        for (int f = 0; f < DD; ++f) o += z2s[b][f] * W2[f];
        out[b] = 1.f / (1.f + expf(-o));
    }
}

// ---------------------------------------------------------------------------
extern "C" void kernel_launch(void* const* d_in, const int* in_sizes, int n_in,
                              void* d_out, int out_size, void* d_ws, size_t ws_size,
                              hipStream_t stream)
{
    const float* x    = (const float*)d_in[0];
    const float* adj  = (const float*)d_in[1];
    const float* mask = (const float*)d_in[2];
    const float* t    = (const float*)d_in[3];
    const float* Wg   = (const float*)d_in[4];
    const float* bg   = (const float*)d_in[5];
    const float* Wt   = (const float*)d_in[6];
    const float* bt   = (const float*)d_in[7];
    const float* W0   = (const float*)d_in[8];
    const float* b0   = (const float*)d_in[9];
    const float* W1   = (const float*)d_in[10];
    const float* b1   = (const float*)d_in[11];
    const float* W2   = (const float*)d_in[12];
    const float* b2   = (const float*)d_in[13];
    float* out = (float*)d_out;

    __bf16* hT    = (__bf16*)d_ws;                                    // 4 MB
    float* pooled = (float*)((char*)d_ws + (size_t)BB * DD * NN * 2); // 2 KB

    kernA<<<BB * NN / 64, 256, 0, stream>>>(x, Wg, bg, hT, pooled);
    kernB<<<BB * NN / RT, 512, 0, stream>>>(adj, hT, mask, pooled);
    kernC<<<1, 512, 0, stream>>>(mask, t, Wt, bt, W0, b0, W1, b1, W2, b2,
                                 pooled, out);
}

// Round 10
// 249.045 us; speedup vs baseline: 1.1674x; 1.1674x over previous
//
#include <hip/hip_runtime.h>
#include <hip/hip_bf16.h>
#include <math.h>

#define BB 8
#define NN 4096
#define FF 100
#define DD 64
#define BK 64
#define RT 128    // rows per block tile

typedef __bf16 bf16x8 __attribute__((ext_vector_type(8)));
typedef float f32x4 __attribute__((ext_vector_type(4)));

// ---------------------------------------------------------------------------
// Kernel A: hT[b][d][m] = bf16( x[b,m,:] @ Wg[:,d] + bg[d] )  (transposed)
// Also zeroes pooled[] (blocks 0-1). (unchanged — verified)
// ---------------------------------------------------------------------------
__global__ __launch_bounds__(256) void kernA(
    const float* __restrict__ x, const float* __restrict__ Wg,
    const float* __restrict__ bg, __bf16* __restrict__ hT,
    float* __restrict__ pooled)
{
    __shared__ float lds[64][65];
    int tid = threadIdx.x;
    int g = blockIdx.x * 256 + tid;
    if (g < BB * DD) pooled[g] = 0.0f;

    int b  = blockIdx.x >> 6;
    int m0 = (blockIdx.x & 63) * 64;
    int d  = tid & 63;
    int mg = tid >> 6;

    float acc[16];
    float bias = bg[d];
    #pragma unroll
    for (int j = 0; j < 16; ++j) acc[j] = bias;

    const float* xbase = x + ((size_t)b * NN + m0 + mg * 16) * FF;
    for (int f4 = 0; f4 < FF / 4; ++f4) {
        float wg0 = Wg[(f4 * 4 + 0) * DD + d];
        float wg1 = Wg[(f4 * 4 + 1) * DD + d];
        float wg2 = Wg[(f4 * 4 + 2) * DD + d];
        float wg3 = Wg[(f4 * 4 + 3) * DD + d];
        #pragma unroll
        for (int j = 0; j < 16; ++j) {
            float4 xv = *reinterpret_cast<const float4*>(xbase + j * FF + f4 * 4);
            acc[j] += xv.x * wg0 + xv.y * wg1 + xv.z * wg2 + xv.w * wg3;
        }
    }
    #pragma unroll
    for (int j = 0; j < 16; ++j) lds[mg * 16 + j][d] = acc[j];
    __syncthreads();

    int lane = tid & 63;
    int dg   = tid >> 6;
    size_t obase = ((size_t)b * DD + dg * 16) * NN + m0 + lane;
    #pragma unroll
    for (int j = 0; j < 16; ++j)
        hT[obase + (size_t)j * NN] = (__bf16)lds[lane][dg * 16 + j];
}

// ---------------------------------------------------------------------------
// Kernel B v10 = R8 geometry (RT=128, BK=64, 512 thr, grid 256, XCD swizzle,
// identical LDS content/compute/epilogue) with staging swapped DMA -> reg
// path, PROPERLY scheduled (unlike R9): 5 global_load_dwordx4 issued at the
// TOP of each body (full-body latency cover), counted vmcnt(5) before the
// ds_writes (next tile's loads stay in flight), one barrier per tile,
// unrolled x2 with named ra/rb register sets (static indexing).
// Contiguous global reads; swizzle applied on the ds_write DEST (reg path
// has no DMA linear-dest constraint), so LDS content == R8's exactly.
// ---------------------------------------------------------------------------
__global__ __launch_bounds__(512) void kernB(
    const float* __restrict__ adj, const __bf16* __restrict__ hT,
    const float* __restrict__ mask, float* __restrict__ pooled)
{
    __shared__ float  aL[2][RT * BK];   // 2 x 32 KB
    __shared__ __bf16 hL[2][DD * BK];   // 2 x 8 KB

    int l   = blockIdx.x;               // 0..255
    int bb  = l & 7;                    // batch == XCD (l % 8 round-robin)
    int n0  = (l >> 3) * RT;
    int tid = threadIdx.x;
    int w    = tid >> 6;                // 0..7
    int lane = tid & 63;
    int l15  = lane & 15;
    int kg   = lane >> 4;
    int rowL = w * 16 + l15;
    int rsw  = l15;                     // rowL & 15 == l15
    int dsw  = l15 & 7;

    f32x4 acc[4];
    #pragma unroll
    for (int c = 0; c < 4; ++c) acc[c] = (f32x4){0.f, 0.f, 0.f, 0.f};

    const float*  adjB = adj + ((size_t)bb * NN + n0) * NN;
    const __bf16* hTB  = hT + (size_t)bb * DD * NN;

    // staging geometry: contiguous global src, swizzled LDS dest granule
    const float* srcA[4];
    int dstA[4];
    #pragma unroll
    for (int i = 0; i < 4; ++i) {
        int p    = i * 512 + tid;       // granule 0..2047
        int row  = p >> 4;
        int slot = p & 15;
        srcA[i]  = adjB + (size_t)row * NN + slot * 4;
        dstA[i]  = row * 16 + (slot ^ (row & 15));
    }
    const __bf16* srcH;
    int dstH;
    {
        int p    = tid;                 // granule 0..511
        int d    = p >> 3;
        int slot = p & 7;
        srcH     = hTB + (size_t)d * NN + slot * 8;
        dstH     = d * 8 + (slot ^ (d & 7));
    }

    float4 ra[5], rb[5];

#define LOADS(rg, k0) do {                                                   \
        _Pragma("unroll")                                                    \
        for (int i_ = 0; i_ < 4; ++i_)                                       \
            rg[i_] = *reinterpret_cast<const float4*>(srcA[i_] + (k0));      \
        rg[4] = *reinterpret_cast<const float4*>(srcH + (k0));               \
    } while (0)

#define WRITES(rg, buf) do {                                                 \
        _Pragma("unroll")                                                    \
        for (int i_ = 0; i_ < 4; ++i_)                                       \
            *reinterpret_cast<float4*>(                                      \
                reinterpret_cast<char*>(&aL[buf][0]) +                       \
                (size_t)dstA[i_] * 16) = rg[i_];                             \
        *reinterpret_cast<float4*>(                                          \
            reinterpret_cast<char*>(&hL[buf][0]) + (size_t)dstH * 16) = rg[4];\
    } while (0)

    auto compute = [&](int buf) {
        const float*  aB = &aL[buf][rowL * BK];
        const __bf16* hB = &hL[buf][0];
        #pragma unroll
        for (int kk = 0; kk < 2; ++kk) {
            int s0 = kk * 8 + kg * 2;
            f32x4 alo = *(const f32x4*)(aB + ((s0    ) ^ rsw) * 4);
            f32x4 ahi = *(const f32x4*)(aB + ((s0 + 1) ^ rsw) * 4);
            bf16x8 af;
            af[0] = (__bf16)alo[0]; af[1] = (__bf16)alo[1];
            af[2] = (__bf16)alo[2]; af[3] = (__bf16)alo[3];
            af[4] = (__bf16)ahi[0]; af[5] = (__bf16)ahi[1];
            af[6] = (__bf16)ahi[2]; af[7] = (__bf16)ahi[3];
            int slB = (kk * 4 + kg) ^ dsw;
            #pragma unroll
            for (int c = 0; c < 4; ++c) {
                const __bf16* bp = hB + (c * 16 + l15) * BK + slB * 8;
                acc[c] = __builtin_amdgcn_mfma_f32_16x16x32_bf16(
                    af, *(const bf16x8*)bp, acc[c], 0, 0, 0);
            }
        }
    };

    // prologue: tiles 0 and 1 in flight; buf0 written and published
    LOADS(ra, 0);
    LOADS(rb, BK);
    asm volatile("s_waitcnt vmcnt(5)" ::: "memory");   // ra done, rb in flight
    WRITES(ra, 0);
    asm volatile("s_waitcnt lgkmcnt(0)" ::: "memory");
    __builtin_amdgcn_s_barrier();

    for (int it = 0; it < 32; ++it) {
        int t = 2 * it;
        // even body: compute tile t (buf0); rb holds t+1; load t+2 -> ra
        if (it < 31) LOADS(ra, (t + 2) * BK);
        compute(0);
        if (it < 31) asm volatile("s_waitcnt vmcnt(5)" ::: "memory");
        else         asm volatile("s_waitcnt vmcnt(0)" ::: "memory");
        WRITES(rb, 1);
        asm volatile("s_waitcnt lgkmcnt(0)" ::: "memory");
        __builtin_amdgcn_s_barrier();

        // odd body: compute tile t+1 (buf1); ra holds t+2; load t+3 -> rb
        if (it < 31) {
            LOADS(rb, (t + 3) * BK);
            compute(1);
            asm volatile("s_waitcnt vmcnt(5)" ::: "memory");
            WRITES(ra, 0);
            asm volatile("s_waitcnt lgkmcnt(0)" ::: "memory");
            __builtin_amdgcn_s_barrier();
        } else {
            compute(1);                 // final tile 63
        }
    }
#undef LOADS
#undef WRITES

    // Epilogue: D layout col = lane&15, row = (lane>>4)*4 + j  [m89 verified]
    float mk[4];
    int growbase = n0 + w * 16 + kg * 4;
    #pragma unroll
    for (int j = 0; j < 4; ++j) mk[j] = mask[bb * NN + growbase + j];
    #pragma unroll
    for (int c = 0; c < 4; ++c) {
        float s = 0.f;
        #pragma unroll
        for (int j = 0; j < 4; ++j) s += fmaxf(acc[c][j], 0.f) * mk[j];
        s += __shfl_xor(s, 16);
        s += __shfl_xor(s, 32);
        if (lane < 16)
            atomicAdd(&pooled[bb * DD + c * 16 + lane], s);
    }
}

// ---------------------------------------------------------------------------
// Kernel C: pooled normalize + time MLP + classifier + sigmoid. 1 block.
// ---------------------------------------------------------------------------
__global__ __launch_bounds__(512) void kernC(
    const float* __restrict__ mask, const float* __restrict__ t_in,
    const float* __restrict__ Wt, const float* __restrict__ bt,
    const float* __restrict__ W0, const float* __restrict__ b0,
    const float* __restrict__ W1, const float* __restrict__ b1,
    const float* __restrict__ W2, const float* __restrict__ b2,
    const float* __restrict__ pooled, float* __restrict__ out)
{
    __shared__ float msum[BB];
    __shared__ float zs[BB][2 * DD];
    __shared__ float z1s[BB][DD];
    __shared__ float z2s[BB][DD];

    int tid  = threadIdx.x;
    int b    = tid >> 6;
    int lane = tid & 63;

    float s = 0.f;
    for (int i = lane; i < NN; i += 64) s += mask[b * NN + i];
    s += __shfl_xor(s, 32); s += __shfl_xor(s, 16);
    s += __shfl_xor(s, 8);  s += __shfl_xor(s, 4);
    s += __shfl_xor(s, 2);  s += __shfl_xor(s, 1);
    if (lane == 0) msum[b] = s;
    __syncthreads();

    float ms  = fmaxf(msum[b], 1.0f);
    float pv  = pooled[b * DD + lane] / ms;
    float tev = t_in[b] * Wt[lane] + bt[lane];
    zs[b][lane]      = pv;
    zs[b][DD + lane] = tev;
    __syncthreads();

    float a = b0[lane];
    for (int f = 0; f < 2 * DD; ++f) a += zs[b][f] * W0[f * DD + lane];
    z1s[b][lane] = fmaxf(a, 0.f);
    __syncthreads();

    a = b1[lane];
    for (int f = 0; f < DD; ++f) a += z1s[b][f] * W1[f * DD + lane];
    z2s[b][lane] = fmaxf(a, 0.f);
    __syncthreads();

    if (lane == 0) {
        float o = b2[0];
        for (int f = 0; f < DD; ++f) o += z2s[b][f] * W2[f];
        out[b] = 1.f / (1.f + expf(-o));
    }
}

// ---------------------------------------------------------------------------
extern "C" void kernel_launch(void* const* d_in, const int* in_sizes, int n_in,
                              void* d_out, int out_size, void* d_ws, size_t ws_size,
                              hipStream_t stream)
{
    const float* x    = (const float*)d_in[0];
    const float* adj  = (const float*)d_in[1];
    const float* mask = (const float*)d_in[2];
    const float* t    = (const float*)d_in[3];
    const float* Wg   = (const float*)d_in[4];
    const float* bg   = (const float*)d_in[5];
    const float* Wt   = (const float*)d_in[6];
    const float* bt   = (const float*)d_in[7];
    const float* W0   = (const float*)d_in[8];
    const float* b0   = (const float*)d_in[9];
    const float* W1   = (const float*)d_in[10];
    const float* b1   = (const float*)d_in[11];
    const float* W2   = (const float*)d_in[12];
    const float* b2   = (const float*)d_in[13];
    float* out = (float*)d_out;

    __bf16* hT    = (__bf16*)d_ws;                                    // 4 MB
    float* pooled = (float*)((char*)d_ws + (size_t)BB * DD * NN * 2); // 2 KB

    kernA<<<BB * NN / 64, 256, 0, stream>>>(x, Wg, bg, hT, pooled);
    kernB<<<BB * NN / RT, 512, 0, stream>>>(adj, hT, mask, pooled);
    kernC<<<1, 512, 0, stream>>>(mask, t, Wt, bt, W0, b0, W1, b1, W2, b2,
                                 pooled, out);
}

// Round 11
// 153.626 us; speedup vs baseline: 1.8925x; 1.6211x over previous
//
#include <hip/hip_runtime.h>
#include <hip/hip_bf16.h>
#include <math.h>

#define BB 8
#define NN 4096
#define FF 100
#define DD 64
#define BK 64
#define RT 128    // rows per block tile (kernB)

typedef __bf16 bf16x8 __attribute__((ext_vector_type(8)));
typedef float f32x4 __attribute__((ext_vector_type(4)));

__device__ __forceinline__ void gload16(const void* g, void* l) {
    __builtin_amdgcn_global_load_lds(
        (const __attribute__((address_space(1))) unsigned int*)g,
        (__attribute__((address_space(3))) unsigned int*)l, 16, 0, 0);
}
// SC1|NT (aux=18): device-scope read -> cannot allocate in the per-XCD L2
// (not device-coherent) -> bypasses the L2 miss-fill stage implicated as the
// ~3.5 TB/s adj wall. L3 (device-level) still caches. Read-only => safe.
__device__ __forceinline__ void gload16sc(const void* g, void* l) {
    __builtin_amdgcn_global_load_lds(
        (const __attribute__((address_space(1))) unsigned int*)g,
        (__attribute__((address_space(3))) unsigned int*)l, 16, 0, 18);
}

// ---------------------------------------------------------------------------
// Kernel A v2: hT[b][d][m] = bf16( x[b,m,:] @ Wg[:,d] + bg[d] ) via MFMA.
// Old fp32-VALU version was FMA-bound (~27 us floor). Here: Wg -> LDS as
// bf16 WgT[64][136] zero-padded K 100->128; per wave 16-row strip, 4 col
// tiles, 4 K-chunks of 16x16x32 MFMA; bias added in epilogue; coalesced
// hT write via the old verified LDS-transpose. Zeroes pooled[] (blocks 0-1).
// Fragment convention identical to kernB's (absmax-0 verified).
// ---------------------------------------------------------------------------
__global__ __launch_bounds__(256) void kernA(
    const float* __restrict__ x, const float* __restrict__ Wg,
    const float* __restrict__ bg, __bf16* __restrict__ hT,
    float* __restrict__ pooled)
{
    __shared__ __bf16 wgT[DD][136];     // 17 KB, K-padded (only 0..127 read)
    __shared__ float  lds[64][65];      // 16.6 KB transpose buffer

    int tid = threadIdx.x;
    int g = blockIdx.x * 256 + tid;
    if (g < BB * DD) pooled[g] = 0.0f;

    int b  = blockIdx.x >> 6;
    int m0 = (blockIdx.x & 63) * 64;
    int lane = tid & 63;
    int w    = tid >> 6;                // wave 0..3
    int l15  = lane & 15;
    int kg   = lane >> 4;

    // phase 1: WgT (zero-pad then fill)
    for (int i = tid; i < DD * 136; i += 256)
        wgT[i / 136][i % 136] = (__bf16)0.0f;
    __syncthreads();
    for (int i = tid; i < FF * DD; i += 256) {
        int k = i >> 6, d = i & 63;
        wgT[d][k] = (__bf16)Wg[i];
    }
    __syncthreads();

    // phase 2: MFMA  (A: row = l15, k = kg*8+e ; B: col = l15, same k)
    f32x4 acc[4];
    #pragma unroll
    for (int c = 0; c < 4; ++c) acc[c] = (f32x4){0.f, 0.f, 0.f, 0.f};

    int m = m0 + w * 16 + l15;
    const float* xrow = x + ((size_t)b * NN + m) * FF;

    #pragma unroll
    for (int kc = 0; kc < 4; ++kc) {
        bf16x8 af;
        if (kc < 3) {
            float4 xa = *reinterpret_cast<const float4*>(xrow + kc * 32 + kg * 8);
            float4 xb = *reinterpret_cast<const float4*>(xrow + kc * 32 + kg * 8 + 4);
            af[0] = (__bf16)xa.x; af[1] = (__bf16)xa.y;
            af[2] = (__bf16)xa.z; af[3] = (__bf16)xa.w;
            af[4] = (__bf16)xb.x; af[5] = (__bf16)xb.y;
            af[6] = (__bf16)xb.z; af[7] = (__bf16)xb.w;
        } else {
            // k = 96..127: only kg==0 lanes carry k 96..99; rest zero
            float4 xa = (kg == 0)
                ? *reinterpret_cast<const float4*>(xrow + 96)
                : (float4){0.f, 0.f, 0.f, 0.f};
            af[0] = (__bf16)xa.x; af[1] = (__bf16)xa.y;
            af[2] = (__bf16)xa.z; af[3] = (__bf16)xa.w;
            af[4] = (__bf16)0.f;  af[5] = (__bf16)0.f;
            af[6] = (__bf16)0.f;  af[7] = (__bf16)0.f;
        }
        #pragma unroll
        for (int c = 0; c < 4; ++c) {
            bf16x8 bv = *reinterpret_cast<const bf16x8*>(
                &wgT[c * 16 + l15][kc * 32 + kg * 8]);
            acc[c] = __builtin_amdgcn_mfma_f32_16x16x32_bf16(af, bv, acc[c], 0, 0, 0);
        }
    }

    // phase 3: bias + transpose-LDS + coalesced hT write (old verified path)
    #pragma unroll
    for (int c = 0; c < 4; ++c) {
        float bias = bg[c * 16 + l15];
        #pragma unroll
        for (int j = 0; j < 4; ++j)
            lds[w * 16 + kg * 4 + j][c * 16 + l15] = acc[c][j] + bias;
    }
    __syncthreads();

    int dg = tid >> 6;
    size_t obase = ((size_t)b * DD + dg * 16) * NN + m0 + lane;
    #pragma unroll
    for (int j = 0; j < 16; ++j)
        hT[obase + (size_t)j * NN] = (__bf16)lds[lane][dg * 16 + j];
}

// ---------------------------------------------------------------------------
// Kernel B v11 = R8 (best: DMA staging, RT=128, BK=64, triple-buffer,
// counted vmcnt(5), XCD-bijective swizzle) with adj loads at SC1|NT
// (device scope -> L2-fill bypass). hT loads keep default (L2-cached).
// ---------------------------------------------------------------------------
__global__ __launch_bounds__(512) void kernB(
    const float* __restrict__ adj, const __bf16* __restrict__ hT,
    const float* __restrict__ mask, float* __restrict__ pooled)
{
    __shared__ float  aL[3][RT * BK];   // 3 x 32 KB
    __shared__ __bf16 hL[3][DD * BK];   // 3 x 8 KB

    int l   = blockIdx.x;               // 0..255
    int bb  = l & 7;                    // batch == XCD (l % 8 round-robin)
    int n0  = (l >> 3) * RT;            // rowgroup base
    int tid = threadIdx.x;
    int w    = tid >> 6;                // 0..7
    int lane = tid & 63;
    int l15  = lane & 15;
    int kg   = lane >> 4;
    int rowL = w * 16 + l15;            // 0..127
    int rsw  = rowL & 15;               // adj swizzle key
    int dsw  = l15 & 7;                 // hT swizzle key

    f32x4 acc[4];
    #pragma unroll
    for (int c = 0; c < 4; ++c) acc[c] = (f32x4){0.f, 0.f, 0.f, 0.f};

    const float*  adjB = adj + ((size_t)bb * NN + n0) * NN;
    const __bf16* hTB  = hT + (size_t)bb * DD * NN;

    auto stage = [&](int buf, int k0) {
        #pragma unroll
        for (int i = 0; i < 4; ++i) {              // adj: 128 rows x 256 B
            int p    = i * 512 + tid;              // granule 0..2047
            int row  = p >> 4;
            int slot = p & 15;
            int ss   = slot ^ (row & 15);
            const float* gp = adjB + (size_t)row * NN + k0 + ss * 4;
            gload16sc(gp, (char*)(&aL[buf][0]) + (size_t)p * 16);
        }
        {                                          // hT: 64 d x 128 B
            int p    = tid;                        // granule 0..511
            int d    = p >> 3;
            int slot = p & 7;
            int ss   = slot ^ (d & 7);
            const __bf16* gp = hTB + (size_t)d * NN + k0 + ss * 8;
            gload16(gp, (char*)(&hL[buf][0]) + (size_t)p * 16);
        }
    };

    const int NSTEP = NN / BK;          // 64
    stage(0, 0);
    stage(1, BK);

    for (int step = 0; step < NSTEP; ++step) {
        if (step < NSTEP - 1) {
            asm volatile("s_waitcnt vmcnt(5) lgkmcnt(0)" ::: "memory");
        } else {
            asm volatile("s_waitcnt vmcnt(0) lgkmcnt(0)" ::: "memory");
        }
        __builtin_amdgcn_s_barrier();
        if (step + 2 < NSTEP) stage((step + 2) % 3, (step + 2) * BK);

        int cur = step % 3;
        const float*  aB = &aL[cur][rowL * BK];
        const __bf16* hB = &hL[cur][0];
        #pragma unroll
        for (int kk = 0; kk < 2; ++kk) {
            int s0 = kk * 8 + kg * 2;
            f32x4 alo = *(const f32x4*)(aB + ((s0    ) ^ rsw) * 4);
            f32x4 ahi = *(const f32x4*)(aB + ((s0 + 1) ^ rsw) * 4);
            bf16x8 af;
            af[0] = (__bf16)alo[0]; af[1] = (__bf16)alo[1];
            af[2] = (__bf16)alo[2]; af[3] = (__bf16)alo[3];
            af[4] = (__bf16)ahi[0]; af[5] = (__bf16)ahi[1];
            af[6] = (__bf16)ahi[2]; af[7] = (__bf16)ahi[3];
            int slB = (kk * 4 + kg) ^ dsw;
            #pragma unroll
            for (int c = 0; c < 4; ++c) {
                const __bf16* bp = hB + (c * 16 + l15) * BK + slB * 8;
                acc[c] = __builtin_amdgcn_mfma_f32_16x16x32_bf16(
                    af, *(const bf16x8*)bp, acc[c], 0, 0, 0);
            }
        }
    }

    // Epilogue: D layout col = lane&15, row = (lane>>4)*4 + j  [m89 verified]
    float mk[4];
    int growbase = n0 + w * 16 + kg * 4;
    #pragma unroll
    for (int j = 0; j < 4; ++j) mk[j] = mask[bb * NN + growbase + j];
    #pragma unroll
    for (int c = 0; c < 4; ++c) {
        float s = 0.f;
        #pragma unroll
        for (int j = 0; j < 4; ++j) s += fmaxf(acc[c][j], 0.f) * mk[j];
        s += __shfl_xor(s, 16);
        s += __shfl_xor(s, 32);
        if (lane < 16)
            atomicAdd(&pooled[bb * DD + c * 16 + lane], s);
    }
}

// ---------------------------------------------------------------------------
// Kernel C: pooled normalize + time MLP + classifier + sigmoid. 1 block.
// ---------------------------------------------------------------------------
__global__ __launch_bounds__(512) void kernC(
    const float* __restrict__ mask, const float* __restrict__ t_in,
    const float* __restrict__ Wt, const float* __restrict__ bt,
    const float* __restrict__ W0, const float* __restrict__ b0,
    const float* __restrict__ W1, const float* __restrict__ b1,
    const float* __restrict__ W2, const float* __restrict__ b2,
    const float* __restrict__ pooled, float* __restrict__ out)
{
    __shared__ float msum[BB];
    __shared__ float zs[BB][2 * DD];
    __shared__ float z1s[BB][DD];
    __shared__ float z2s[BB][DD];

    int tid  = threadIdx.x;
    int b    = tid >> 6;
    int lane = tid & 63;

    float s = 0.f;
    for (int i = lane; i < NN; i += 64) s += mask[b * NN + i];
    s += __shfl_xor(s, 32); s += __shfl_xor(s, 16);
    s += __shfl_xor(s, 8);  s += __shfl_xor(s, 4);
    s += __shfl_xor(s, 2);  s += __shfl_xor(s, 1);
    if (lane == 0) msum[b] = s;
    __syncthreads();

    float ms  = fmaxf(msum[b], 1.0f);
    float pv  = pooled[b * DD + lane] / ms;
    float tev = t_in[b] * Wt[lane] + bt[lane];
    zs[b][lane]      = pv;
    zs[b][DD + lane] = tev;
    __syncthreads();

    float a = b0[lane];
    for (int f = 0; f < 2 * DD; ++f) a += zs[b][f] * W0[f * DD + lane];
    z1s[b][lane] = fmaxf(a, 0.f);
    __syncthreads();

    a = b1[lane];
    for (int f = 0; f < DD; ++f) a += z1s[b][f] * W1[f * DD + lane];
    z2s[b][lane] = fmaxf(a, 0.f);
    __syncthreads();

    if (lane == 0) {
        float o = b2[0];
        for (int f = 0; f < DD; ++f) o += z2s[b][f] * W2[f];
        out[b] = 1.f / (1.f + expf(-o));
    }
}

// ---------------------------------------------------------------------------
extern "C" void kernel_launch(void* const* d_in, const int* in_sizes, int n_in,
                              void* d_out, int out_size, void* d_ws, size_t ws_size,
                              hipStream_t stream)
{
    const float* x    = (const float*)d_in[0];
    const float* adj  = (const float*)d_in[1];
    const float* mask = (const float*)d_in[2];
    const float* t    = (const float*)d_in[3];
    const float* Wg   = (const float*)d_in[4];
    const float* bg   = (const float*)d_in[5];
    const float* Wt   = (const float*)d_in[6];
    const float* bt   = (const float*)d_in[7];
    const float* W0   = (const float*)d_in[8];
    const float* b0   = (const float*)d_in[9];
    const float* W1   = (const float*)d_in[10];
    const float* b1   = (const float*)d_in[11];
    const float* W2   = (const float*)d_in[12];
    const float* b2   = (const float*)d_in[13];
    float* out = (float*)d_out;

    __bf16* hT    = (__bf16*)d_ws;                                    // 4 MB
    float* pooled = (float*)((char*)d_ws + (size_t)BB * DD * NN * 2); // 2 KB

    kernA<<<BB * NN / 64, 256, 0, stream>>>(x, Wg, bg, hT, pooled);
    kernB<<<BB * NN / RT, 512, 0, stream>>>(adj, hT, mask, pooled);
    kernC<<<1, 512, 0, stream>>>(mask, t, Wt, bt, W0, b0, W1, b1, W2, b2,
                                 pooled, out);
}